// Round 14
// baseline (185.527 us; speedup 1.0000x reference)
//
#include <hip/hip_runtime.h>
#include <math.h>

// Problem constants (fixed by the reference)
static constexpr int N    = 50000;   // nodes
static constexpr int E    = 800000;  // edges
static constexpr int TE   = E + N;   // edges + self loops
static constexpr int NC   = 16;      // conv1d channels
static constexpr int TOT  = 193;     // concat dim
static constexpr int NB   = (N + 255) / 256;  // 196 scan blocks
static constexpr int DP   = 16;      // deg padding: 1 counter / 64B line
static constexpr int XBF_BLOCKS = (N * 64 / 4) / 256;  // 3125

// K-buffer layout (floats)
static constexpr int KQ1 = 0;      // Q1[64][16] = W0 . cw1^T
static constexpr int KQ2 = 1024;   // Q2[64][16] = (W0W1) . cw2^T
static constexpr int KQ3 = 2048;   // Q3[64][16] = (W0W1) . (W2 . cw3^T)
static constexpr int KV  = 3072;   // v[64] = (W0W1) . (W2 W3)
static constexpr int KU1 = 3136;   // u1[16] = (b0W1)cw2^T + (b1W2)cw3^T
static constexpr int KU2 = 3152;   // u2[16] = (b0W1W2)cw3^T
static constexpr int KD  = 3168;   // d[16]  = b0 cw1^T + b1 cw2^T + b2 cw3^T + cb
static constexpr int KSC = 3184;   // alpha=(b0W1W2)W3, beta=(b1W2)W3, gamma=b2.W3
static constexpr int KSZ = 3200;

__device__ __forceinline__ unsigned short f2bf(float f) {
    union { float f; unsigned int i; } v; v.f = f;
    unsigned int b = v.i + 0x7FFFu + ((v.i >> 16) & 1u);   // RNE
    return (unsigned short)(b >> 16);
}

// ---------------- fused setup + x->bf16 + degp zeroing ----------------
// Blocks 0..XBF_BLOCKS-1: convert x to bf16 (4 floats/thread) + zero degp.
// Block XBF_BLOCKS: weight-product setup (1 CU) — runs CONCURRENTLY.
__global__ __launch_bounds__(256) void k_setup_xbf(
    const float* __restrict__ x, ushort* __restrict__ xb, int* __restrict__ degp,
    const float* __restrict__ W0, const float* __restrict__ b0,
    const float* __restrict__ W1, const float* __restrict__ b1,
    const float* __restrict__ W2, const float* __restrict__ b2,
    const float* __restrict__ W3, const float* __restrict__ b3,
    const float* __restrict__ cw, const float* __restrict__ cb,
    float* __restrict__ K) {
    const int t = threadIdx.x;
    if (blockIdx.x < XBF_BLOCKS) {
        int i = blockIdx.x * 256 + t;
        degp[i] = 0;                       // N*DP == N*64/4 exactly
        float4 v = ((const float4*)x)[i];
        ushort4 o;
        o.x = f2bf(v.x); o.y = f2bf(v.y); o.z = f2bf(v.z); o.w = f2bf(v.w);
        ((ushort4*)xb)[i] = o;
        return;
    }
    // ---- setup path (single block) ----
    __shared__ float W0s[4096], W1s[4096], W2s[4096], P2s[4096];
    __shared__ float C1[1024], C2[1024], C3[1024], R3s[1024];
    __shared__ float W3s[64], b0s[64], b1s[64], b2s[64];
    __shared__ float r3[64], rb1[64], rb2[64], rb12[64];
    const int k = t >> 2, q = t & 3;

    for (int i = t; i < 4096; i += 256) {
        W0s[i] = W0[i]; W1s[i] = W1[i]; W2s[i] = W2[i];
    }
    for (int i = t; i < 1024; i += 256) {
        int j = i >> 4, c = i & 15;       // C[j][c] = cw[c, off + j]
        C1[i] = cw[c * TOT + j];
        C2[i] = cw[c * TOT + 64 + j];
        C3[i] = cw[c * TOT + 128 + j];
    }
    if (t < 64) { W3s[t] = W3[t]; b0s[t] = b0[t]; b1s[t] = b1[t]; b2s[t] = b2[t]; }
    __syncthreads();

    // phase 1: P2 = W0 W1 ; R3 = W2 C3 ; r3 = W2 W3 ; rb1 = b0 W1 ; rb2 = b1 W2
    {
        const int j0 = q * 16;
        float acc[16];
#pragma unroll
        for (int jj = 0; jj < 16; ++jj) acc[jj] = 0.f;
        for (int m = 0; m < 64; ++m) {
            float w = W0s[k * 64 + m];
#pragma unroll
            for (int jj = 0; jj < 16; ++jj) acc[jj] += w * W1s[m * 64 + j0 + jj];
        }
#pragma unroll
        for (int jj = 0; jj < 16; ++jj) P2s[k * 64 + j0 + jj] = acc[jj];
    }
    {
        const int c0 = q * 4;
        float acc[4] = {0.f, 0.f, 0.f, 0.f};
        for (int j = 0; j < 64; ++j) {
            float w = W2s[k * 64 + j];
#pragma unroll
            for (int cc = 0; cc < 4; ++cc) acc[cc] += w * C3[j * 16 + c0 + cc];
        }
#pragma unroll
        for (int cc = 0; cc < 4; ++cc) R3s[k * 16 + c0 + cc] = acc[cc];
    }
    if (q == 0) {
        float a = 0.f;
        for (int j = 0; j < 64; ++j) a += W2s[k * 64 + j] * W3s[j];
        r3[k] = a;
    }
    if (q == 1) {
        float a = 0.f;
        for (int m = 0; m < 64; ++m) a += b0s[m] * W1s[m * 64 + k];
        rb1[k] = a;
    }
    if (q == 2) {
        float a = 0.f;
        for (int m = 0; m < 64; ++m) a += b1s[m] * W2s[m * 64 + k];
        rb2[k] = a;
    }
    __syncthreads();

    // phase 2: Q1 = W0 C1 ; Q2 = P2 C2 ; Q3 = P2 R3 ; v = P2 r3 ; rb12 = rb1 W2
    {
        const int c0 = q * 4;
        float q1[4] = {0,0,0,0}, q2[4] = {0,0,0,0}, q3[4] = {0,0,0,0};
        for (int j = 0; j < 64; ++j) {
            float w0 = W0s[k * 64 + j], p2 = P2s[k * 64 + j];
#pragma unroll
            for (int cc = 0; cc < 4; ++cc) {
                q1[cc] += w0 * C1[j * 16 + c0 + cc];
                q2[cc] += p2 * C2[j * 16 + c0 + cc];
                q3[cc] += p2 * R3s[j * 16 + c0 + cc];
            }
        }
#pragma unroll
        for (int cc = 0; cc < 4; ++cc) {
            K[KQ1 + k * 16 + c0 + cc] = q1[cc];
            K[KQ2 + k * 16 + c0 + cc] = q2[cc];
            K[KQ3 + k * 16 + c0 + cc] = q3[cc];
        }
    }
    if (q == 3) {
        float a = 0.f;
        for (int j = 0; j < 64; ++j) a += P2s[k * 64 + j] * r3[j];
        K[KV + k] = a;
    }
    if (q == 0) {
        float a = 0.f;
        for (int m = 0; m < 64; ++m) a += rb1[m] * W2s[m * 64 + k];
        rb12[k] = a;
    }
    __syncthreads();

    // phase 3: bias projections
    if (t < 16) {
        float a1 = 0.f, a2 = 0.f, ad = 0.f;
        for (int j = 0; j < 64; ++j) {
            a1 += rb1[j] * C2[j * 16 + t] + rb2[j] * C3[j * 16 + t];
            a2 += rb12[j] * C3[j * 16 + t];
            ad += b0s[j] * C1[j * 16 + t] + b1s[j] * C2[j * 16 + t]
                + b2s[j] * C3[j * 16 + t];
        }
        K[KU1 + t] = a1; K[KU2 + t] = a2; K[KD + t] = ad + cb[t];
    }
    if (t == 0) {
        float al = 0.f, be = 0.f, ga = 0.f;
        for (int j = 0; j < 64; ++j) {
            al += rb12[j] * W3s[j]; be += rb2[j] * W3s[j]; ga += b2s[j] * W3s[j];
        }
        K[KSC + 0] = al; K[KSC + 1] = be; K[KSC + 2] = ga;
    }
}

// ---------------- graph preprocessing ----------------
// 8 split-strided edges / thread: coalesced, 8 atomics in flight per lane
__global__ void k_count(const int* __restrict__ dst, int* __restrict__ degp,
                        int* __restrict__ pos) {
    const int S = E / 8;   // 100000
    int e = blockIdx.x * blockDim.x + threadIdx.x;
    if (e < S) {
        int d[8];
#pragma unroll
        for (int k = 0; k < 8; ++k) d[k] = dst[e + k * S];
        int p[8];
#pragma unroll
        for (int k = 0; k < 8; ++k) p[k] = atomicAdd(&degp[d[k] * DP], 1);
#pragma unroll
        for (int k = 0; k < 8; ++k) pos[e + k * S] = p[k];
    }
}

__global__ __launch_bounds__(256) void k_part(const int* __restrict__ degp,
                                              int* __restrict__ part) {
    __shared__ int red[256];
    const int t = threadIdx.x;
    int i = blockIdx.x * 256 + t;
    int v = (i < N) ? (degp[i * DP] + 1) : 0;   // +1 self-loop
    red[t] = v;
    __syncthreads();
#pragma unroll
    for (int off = 128; off; off >>= 1) {
        if (t < off) red[t] += red[t + off];
        __syncthreads();
    }
    if (t == 0) part[blockIdx.x] = red[0];
}

__global__ __launch_bounds__(256) void k_scanpart(int* __restrict__ part) {
    __shared__ int s[256];
    const int t = threadIdx.x;
    int v = (t < NB) ? part[t] : 0;
    s[t] = v;
    __syncthreads();
#pragma unroll
    for (int off = 1; off < 256; off <<= 1) {
        int u = (t >= off) ? s[t - off] : 0;
        __syncthreads();
        s[t] += u;
        __syncthreads();
    }
    if (t < NB) part[t] = s[t] - v;  // exclusive prefix
}

__global__ __launch_bounds__(256) void k_scatter(const int* __restrict__ degp,
                                                 const int* __restrict__ part,
                                                 int* __restrict__ row_ptr,
                                                 float* __restrict__ dinv) {
    __shared__ int s[256];
    const int t = threadIdx.x;
    int i = blockIdx.x * 256 + t;
    int v = (i < N) ? (degp[i * DP] + 1) : 0;   // +1 self-loop
    s[t] = v;
    __syncthreads();
#pragma unroll
    for (int off = 1; off < 256; off <<= 1) {
        int u = (t >= off) ? s[t - off] : 0;
        __syncthreads();
        s[t] += u;
        __syncthreads();
    }
    if (i < N) {
        int base = part[blockIdx.x];
        row_ptr[i] = base + s[t] - v;
        dinv[i] = rsqrtf((float)v);
        if (i == N - 1) row_ptr[N] = base + s[t];
    }
}

// scatter edges into CSR; NO atomic (slot = pos+1; slot 0 = self-loop)
__global__ void k_fill(const int* __restrict__ src, const int* __restrict__ dst,
                       const int* __restrict__ pos,
                       const int* __restrict__ row_ptr,
                       const float* __restrict__ dinv,
                       int2* __restrict__ edges) {
    int idx = blockIdx.x * blockDim.x + threadIdx.x;
    if (idx < E) {
        int s = src[idx], d = dst[idx];
        int p = row_ptr[d] + 1 + pos[idx];
        edges[p] = make_int2(s, __float_as_int(dinv[s] * dinv[d]));
    } else if (idx < TE) {
        int i = idx - E;
        float dv = dinv[i];
        edges[row_ptr[i]] = make_int2(i, __float_as_int(dv * dv));  // slot 0
    }
}

// ---------------- fused layer: 4 nodes / wave, 8B lanes, edge prefetch -----
// Quarter q (16 lanes) owns node nn; lane m covers feature quad 4m..4m+3.
// Trip t+1's edges load WHILE trip t's gathers are in flight (sw pipeline).
template <int LAYER>
__global__ __launch_bounds__(256) void k_layer(
    const ushort* __restrict__ Min,      // bf16 rows [*,64]
    const int2* __restrict__ edges,
    const int* __restrict__ row_ptr,
    const float* __restrict__ K,
    const float* __restrict__ s1in,
    const float* __restrict__ s2in,
    ushort* __restrict__ Mout,           // bf16 rows [*,64]
    float* __restrict__ s_out,
    float* __restrict__ t4,
    float* __restrict__ out) {
    __shared__ float QT[64 * 17];   // Q_LAYER, padded stride 17
    const int tid = threadIdx.x;
    constexpr int KQ = (LAYER == 0) ? KQ1 : (LAYER == 1) ? KQ2 : KQ3;
    for (int i = tid; i < 1024; i += 256) {
        int j = i >> 4, c = i & 15;
        QT[j * 17 + c] = K[KQ + i];
    }
    const int lane = tid & 63;
    const int w    = tid >> 6;
    const int q    = lane >> 4;          // quarter = node within group of 4
    const int m    = lane & 15;          // feature-quad index
    float v0 = 0.f, v1 = 0.f, v2 = 0.f, v3 = 0.f;
    if constexpr (LAYER == 2) {
        v0 = K[KV + 4 * m + 0]; v1 = K[KV + 4 * m + 1];
        v2 = K[KV + 4 * m + 2]; v3 = K[KV + 4 * m + 3];
    }
    __syncthreads();

    const int nn = blockIdx.x * 16 + w * 4 + q;     // grid = N/16 blocks
    const int rp0 = row_ptr[nn], rp1 = row_ptr[nn + 1];
    const int d = rp1 - rp0;
    int dmax = max(d, __shfl_xor(d, 16));
    dmax = max(dmax, __shfl_xor(dmax, 32));
    const int trips = __builtin_amdgcn_readfirstlane((dmax + 7) >> 3);

    float a0 = 0.f, a1 = 0.f, a2 = 0.f, a3 = 0.f, accs = 0.f;
    int col[8]; float wv[8];
#pragma unroll
    for (int i = 0; i < 8; ++i) {          // prologue: trip-0 edges
        int pi = rp0 + i;
        int pc = min(pi, rp1 - 1);
        int2 e = edges[pc];
        col[i] = e.x;
        wv[i] = (pi < rp1) ? __int_as_float(e.y) : 0.f;
    }
    for (int t = 0; t < trips; ++t) {
        unsigned long long g[8];
#pragma unroll
        for (int i = 0; i < 8; ++i)        // issue gathers (current trip)
            g[i] = *(const unsigned long long*)(Min + col[i] * 64 + 4 * m);
        const int nb = rp0 + (t + 1) * 8;  // prefetch next trip's edges
        int ncol[8]; float nwv[8];
#pragma unroll
        for (int i = 0; i < 8; ++i) {
            int pi = nb + i;
            int pc = min(pi, rp1 - 1);     // clamp: always valid memory
            int2 e = edges[pc];
            ncol[i] = e.x;
            nwv[i] = (pi < rp1) ? __int_as_float(e.y) : 0.f;
        }
        if constexpr (LAYER == 0) {
#pragma unroll
            for (int i = 0; i < 8; ++i) accs += wv[i];
        }
#pragma unroll
        for (int i = 0; i < 8; ++i) {      // consume gathers
            unsigned int lo = (unsigned int)g[i];
            unsigned int hi = (unsigned int)(g[i] >> 32);
            union { unsigned int u; float f; } x0, x1, x2, x3;
            x0.u = lo << 16; x1.u = lo & 0xFFFF0000u;
            x2.u = hi << 16; x3.u = hi & 0xFFFF0000u;
            a0 += wv[i] * x0.f; a1 += wv[i] * x1.f;
            a2 += wv[i] * x2.f; a3 += wv[i] * x3.f;
        }
#pragma unroll
        for (int i = 0; i < 8; ++i) { col[i] = ncol[i]; wv[i] = nwv[i]; }
    }

    if constexpr (LAYER < 2) {
        unsigned long long pk =
              (unsigned long long)f2bf(a0)
            | ((unsigned long long)f2bf(a1) << 16)
            | ((unsigned long long)f2bf(a2) << 32)
            | ((unsigned long long)f2bf(a3) << 48);
        ((unsigned long long*)Mout)[nn * 16 + m] = pk;  // 128B / quarter
    }
    if constexpr (LAYER == 0) {
        if (m == 0) s_out[nn] = accs;   // accs uniform within quarter
    }
    if constexpr (LAYER == 1) {
        // s2[nn] = sum_p wgt * s1[col]  (edges spread over quarter's 16 lanes)
        float ss = 0.f;
        for (int p = rp0 + m; p < rp1; p += 16) {
            int2 e = edges[p];
            ss += __int_as_float(e.y) * s1in[e.x];
        }
        ss += __shfl_xor(ss, 1); ss += __shfl_xor(ss, 2);
        ss += __shfl_xor(ss, 4); ss += __shfl_xor(ss, 8);
        if (m == 0) s_out[nn] = ss;
    }

    float s1n = 0.f, s2n = 0.f;
    if constexpr (LAYER == 2) {
        s1n = s1in[nn]; s2n = s2in[nn];
        float tv = a0 * v0 + a1 * v1 + a2 * v2 + a3 * v3;
        tv += __shfl_xor(tv, 1); tv += __shfl_xor(tv, 2);
        tv += __shfl_xor(tv, 4); tv += __shfl_xor(tv, 8);
        if (m == 0)
            t4[nn] = tv + K[KSC + 0] * s2n + K[KSC + 1] * s1n + K[KSC + 2];
    }

    // projection: lane computes channel c = m for its OWN node (no reduce)
    float r = 0.f;
#pragma unroll
    for (int a = 0; a < 16; ++a) {
        int srcl = (q << 4) + a;     // stay within quarter
        float f0 = __shfl(a0, srcl), f1 = __shfl(a1, srcl);
        float f2 = __shfl(a2, srcl), f3 = __shfl(a3, srcl);
        r += f0 * QT[(4 * a + 0) * 17 + m] + f1 * QT[(4 * a + 1) * 17 + m]
           + f2 * QT[(4 * a + 2) * 17 + m] + f3 * QT[(4 * a + 3) * 17 + m];
    }
    {
        int o = nn * NC + m;         // 64 lanes = 4 full out rows, contiguous
        if constexpr (LAYER == 0) {
            out[o] = K[KD + m] + r;
        } else if constexpr (LAYER == 1) {
            out[o] += r;
        } else {
            out[o] += r + s1n * K[KU1 + m] + s2n * K[KU2 + m];
        }
    }
}

// h4 = b3 + agg(t4); out[n, :] += h4 * conv_w[:, 192]   (thread per node)
__global__ __launch_bounds__(256) void k_agg4_out(
    const float* __restrict__ t4, const int2* __restrict__ edges,
    const int* __restrict__ row_ptr, const float* __restrict__ b3,
    const float* __restrict__ conv_w, float* __restrict__ out) {
    int n = blockIdx.x * blockDim.x + threadIdx.x;
    if (n >= N) return;
    int p0 = row_ptr[n], p1 = row_ptr[n + 1];
    float a0 = 0.f, a1 = 0.f;
    for (int p = p0; p < p1; p += 4) {
        int q0 = min(p, p1 - 1), q1 = min(p + 1, p1 - 1);
        int q2 = min(p + 2, p1 - 1), q3 = min(p + 3, p1 - 1);
        int2 e0 = edges[q0], e1 = edges[q1], e2 = edges[q2], e3 = edges[q3];
        float w0 = __int_as_float(e0.y);
        float w1 = (p + 1 < p1) ? __int_as_float(e1.y) : 0.f;
        float w2 = (p + 2 < p1) ? __int_as_float(e2.y) : 0.f;
        float w3 = (p + 3 < p1) ? __int_as_float(e3.y) : 0.f;
        a0 += w0 * t4[e0.x]; a1 += w1 * t4[e1.x];
        a0 += w2 * t4[e2.x]; a1 += w3 * t4[e3.x];
    }
    float h4 = a0 + a1 + b3[0];
    float4* o4 = (float4*)(out + n * NC);
#pragma unroll
    for (int k = 0; k < 4; ++k) {
        float4 v = o4[k];
        v.x += h4 * conv_w[(4 * k + 0) * TOT + 192];
        v.y += h4 * conv_w[(4 * k + 1) * TOT + 192];
        v.z += h4 * conv_w[(4 * k + 2) * TOT + 192];
        v.w += h4 * conv_w[(4 * k + 3) * TOT + 192];
        o4[k] = v;
    }
}

// ---------------- launch ----------------

extern "C" void kernel_launch(void* const* d_in, const int* in_sizes, int n_in,
                              void* d_out, int out_size, void* d_ws, size_t ws_size,
                              hipStream_t stream) {
    const float* x   = (const float*)d_in[0];
    const int*   ei  = (const int*)d_in[1];
    const int*   src = ei;
    const int*   dst = ei + E;
    const float* W0  = (const float*)d_in[3];
    const float* b0  = (const float*)d_in[4];
    const float* W1  = (const float*)d_in[5];
    const float* b1  = (const float*)d_in[6];
    const float* W2  = (const float*)d_in[7];
    const float* b2  = (const float*)d_in[8];
    const float* W3  = (const float*)d_in[9];
    const float* b3  = (const float*)d_in[10];
    const float* cw  = (const float*)d_in[11];
    const float* cb  = (const float*)d_in[12];
    float* out = (float*)d_out;

    char* p = (char*)d_ws;
    auto alloc = [&](size_t nbytes) {
        char* r = p;
        p += (nbytes + 255) & ~(size_t)255;
        return (void*)r;
    };
    int*    degp    = (int*)alloc((size_t)N * DP * 4);   // padded: 1/line
    int*    pos     = (int*)alloc((size_t)E * 4);
    int*    row_ptr = (int*)alloc((size_t)(N + 1) * 4);
    float*  dinv    = (float*)alloc((size_t)N * 4);
    int*    part    = (int*)alloc((size_t)NB * 4);
    int2*   edges   = (int2*)alloc((size_t)TE * 8);
    ushort* xb      = (ushort*)alloc((size_t)N * 64 * 2);
    ushort* M1      = (ushort*)alloc((size_t)N * 64 * 2);
    ushort* M2      = (ushort*)alloc((size_t)N * 64 * 2);
    float*  s1      = (float*)alloc((size_t)N * 4);
    float*  s2      = (float*)alloc((size_t)N * 4);
    float*  t4      = (float*)alloc((size_t)N * 4);
    float*  K       = (float*)alloc((size_t)KSZ * 4);

    // fused: setup (1 block) runs concurrently with xb conversion + degp zero
    k_setup_xbf<<<XBF_BLOCKS + 1, 256, 0, stream>>>(
        x, xb, degp, W0, b0, W1, b1, W2, b2, W3, b3, cw, cb, K);

    // graph preprocessing
    k_count   <<<(E / 8 + 255) / 256, 256, 0, stream>>>(dst, degp, pos);
    k_part    <<<NB, 256, 0, stream>>>(degp, part);
    k_scanpart<<<1, 256, 0, stream>>>(part);
    k_scatter <<<NB, 256, 0, stream>>>(degp, part, row_ptr, dinv);
    k_fill    <<<(TE + 255) / 256, 256, 0, stream>>>(src, dst, pos, row_ptr, dinv, edges);

    const int layerGrid = N / 16;   // 4 nodes / wave, 4 waves / block

    k_layer<0><<<layerGrid, 256, 0, stream>>>(
        xb, edges, row_ptr, K, nullptr, nullptr, M1, s1, nullptr, out);
    k_layer<1><<<layerGrid, 256, 0, stream>>>(
        M1, edges, row_ptr, K, s1, nullptr, M2, s2, nullptr, out);
    k_layer<2><<<layerGrid, 256, 0, stream>>>(
        M2, edges, row_ptr, K, s1, s2, nullptr, nullptr, t4, out);
    k_agg4_out<<<(N + 255) / 256, 256, 0, stream>>>(t4, edges, row_ptr, b3, cw, out);
}

// Round 15
// 175.308 us; speedup vs baseline: 1.0583x; 1.0583x over previous
//
#include <hip/hip_runtime.h>
#include <math.h>

// Problem constants (fixed by the reference)
static constexpr int N    = 50000;   // nodes
static constexpr int E    = 800000;  // edges
static constexpr int NC   = 16;      // conv1d channels
static constexpr int TOT  = 193;     // concat dim
static constexpr int NB   = (N + 255) / 256;  // 196 scan blocks
static constexpr int DP   = 16;      // deg padding: 1 counter / 64B line

// K-buffer layout (floats)
static constexpr int KQ1 = 0;      // Q1[64][16] = W0 . cw1^T
static constexpr int KQ2 = 1024;   // Q2[64][16] = (W0W1) . cw2^T
static constexpr int KQ3 = 2048;   // Q3[64][16] = (W0W1) . (W2 . cw3^T)
static constexpr int KV  = 3072;   // v[64] = (W0W1) . (W2 W3)
static constexpr int KU1 = 3136;   // u1[16] = (b0W1)cw2^T + (b1W2)cw3^T
static constexpr int KU2 = 3152;   // u2[16] = (b0W1W2)cw3^T
static constexpr int KD  = 3168;   // d[16]  = b0 cw1^T + b1 cw2^T + b2 cw3^T + cb
static constexpr int KSC = 3184;   // alpha=(b0W1W2)W3, beta=(b1W2)W3, gamma=b2.W3
static constexpr int KSZ = 3200;

__device__ __forceinline__ unsigned short f2bf(float f) {
    union { float f; unsigned int i; } v; v.f = f;
    unsigned int b = v.i + 0x7FFFu + ((v.i >> 16) & 1u);   // RNE
    return (unsigned short)(b >> 16);
}

// ---------------- graph preprocessing ----------------
// degp[] zeroed by k_xbf (N*DP == N*64/4 threads). One counter per 64B line
// (kills same-line atomic serialization). degp counts REAL in-edges
// (self-loop = +1 arithmetically; slot 0 of each CSR row, written by k_scatter).

// 4 split-strided edges / thread: coalesced reads+writes, 4 atomics in flight
__global__ void k_count(const int* __restrict__ dst, int* __restrict__ degp,
                        int* __restrict__ pos) {
    int e = blockIdx.x * blockDim.x + threadIdx.x;
    if (e < E / 4) {
        int d0 = dst[e], d1 = dst[e + E / 4];
        int d2 = dst[e + E / 2], d3 = dst[e + 3 * E / 4];
        int p0 = atomicAdd(&degp[d0 * DP], 1);
        int p1 = atomicAdd(&degp[d1 * DP], 1);
        int p2 = atomicAdd(&degp[d2 * DP], 1);
        int p3 = atomicAdd(&degp[d3 * DP], 1);
        pos[e] = p0;
        pos[e + E / 4] = p1;
        pos[e + E / 2] = p2;
        pos[e + 3 * E / 4] = p3;
    }
}

__global__ __launch_bounds__(256) void k_part(const int* __restrict__ degp,
                                              int* __restrict__ part) {
    __shared__ int red[256];
    const int t = threadIdx.x;
    int i = blockIdx.x * 256 + t;
    int v = (i < N) ? (degp[i * DP] + 1) : 0;   // +1 self-loop
    red[t] = v;
    __syncthreads();
#pragma unroll
    for (int off = 128; off; off >>= 1) {
        if (t < off) red[t] += red[t + off];
        __syncthreads();
    }
    if (t == 0) part[blockIdx.x] = red[0];
}

// scatter stage with INLINE prefix of part[] (replaces k_scanpart) and the
// self-loop edge write fused in (replaces k_fill's tail branch).
__global__ __launch_bounds__(256) void k_scatter(const int* __restrict__ degp,
                                                 const int* __restrict__ part,
                                                 int* __restrict__ row_ptr,
                                                 float* __restrict__ dinv,
                                                 int2* __restrict__ edges) {
    __shared__ int s[256];
    __shared__ int red[256];
    const int t = threadIdx.x;
    const int bid = blockIdx.x;
    // base = sum of part[j] for j < bid  (NB = 196 <= 256)
    red[t] = (t < bid && t < NB) ? part[t] : 0;
    __syncthreads();
#pragma unroll
    for (int off = 128; off; off >>= 1) {
        if (t < off) red[t] += red[t + off];
        __syncthreads();
    }
    const int base = red[0];

    int i = bid * 256 + t;
    int v = (i < N) ? (degp[i * DP] + 1) : 0;   // +1 self-loop
    s[t] = v;
    __syncthreads();
#pragma unroll
    for (int off = 1; off < 256; off <<= 1) {
        int u = (t >= off) ? s[t - off] : 0;
        __syncthreads();
        s[t] += u;
        __syncthreads();
    }
    if (i < N) {
        int rp = base + s[t] - v;
        row_ptr[i] = rp;
        float dv = rsqrtf((float)v);
        dinv[i] = dv;
        edges[rp] = make_int2(i, __float_as_int(dv * dv));  // self-loop slot 0
        if (i == N - 1) row_ptr[N] = base + s[t];
    }
}

// scatter real edges into CSR; NO atomic (slot = pos+1; slot 0 = self-loop)
__global__ void k_fill(const int* __restrict__ src, const int* __restrict__ dst,
                       const int* __restrict__ pos,
                       const int* __restrict__ row_ptr,
                       const float* __restrict__ dinv,
                       int2* __restrict__ edges) {
    int idx = blockIdx.x * blockDim.x + threadIdx.x;
    if (idx < E) {
        int s = src[idx], d = dst[idx];
        int p = row_ptr[d] + 1 + pos[idx];
        edges[p] = make_int2(s, __float_as_int(dinv[s] * dinv[d]));
    }
}

// x (fp32) -> xb (bf16), 4 floats / thread; FUSED: zero degp (N*DP = #threads)
__global__ __launch_bounds__(256) void k_xbf(const float* __restrict__ x,
                                             ushort* __restrict__ xb,
                                             int* __restrict__ degp) {
    int i = blockIdx.x * 256 + threadIdx.x;
    if (i * 4 >= N * 64) return;
    degp[i] = 0;                       // N*DP == N*64/4 exactly
    float4 v = ((const float4*)x)[i];
    ushort4 o;
    o.x = f2bf(v.x); o.y = f2bf(v.y); o.z = f2bf(v.z); o.w = f2bf(v.w);
    ((ushort4*)xb)[i] = o;
}

// ---------------- setup: precompute combined weight products ----------------
__global__ __launch_bounds__(256) void k_setup(
    const float* __restrict__ W0, const float* __restrict__ b0,
    const float* __restrict__ W1, const float* __restrict__ b1,
    const float* __restrict__ W2, const float* __restrict__ b2,
    const float* __restrict__ W3, const float* __restrict__ b3,
    const float* __restrict__ cw, const float* __restrict__ cb,
    float* __restrict__ K) {
    __shared__ float W0s[4096], W1s[4096], W2s[4096], P2s[4096];
    __shared__ float C1[1024], C2[1024], C3[1024], R3s[1024];
    __shared__ float W3s[64], b0s[64], b1s[64], b2s[64];
    __shared__ float r3[64], rb1[64], rb2[64], rb12[64];
    const int t = threadIdx.x;
    const int k = t >> 2, q = t & 3;

    for (int i = t; i < 4096; i += 256) {
        W0s[i] = W0[i]; W1s[i] = W1[i]; W2s[i] = W2[i];
    }
    for (int i = t; i < 1024; i += 256) {
        int j = i >> 4, c = i & 15;       // C[j][c] = cw[c, off + j]
        C1[i] = cw[c * TOT + j];
        C2[i] = cw[c * TOT + 64 + j];
        C3[i] = cw[c * TOT + 128 + j];
    }
    if (t < 64) { W3s[t] = W3[t]; b0s[t] = b0[t]; b1s[t] = b1[t]; b2s[t] = b2[t]; }
    __syncthreads();

    // phase 1: P2 = W0 W1 ; R3 = W2 C3 ; r3 = W2 W3 ; rb1 = b0 W1 ; rb2 = b1 W2
    {
        const int j0 = q * 16;
        float acc[16];
#pragma unroll
        for (int jj = 0; jj < 16; ++jj) acc[jj] = 0.f;
        for (int m = 0; m < 64; ++m) {
            float w = W0s[k * 64 + m];
#pragma unroll
            for (int jj = 0; jj < 16; ++jj) acc[jj] += w * W1s[m * 64 + j0 + jj];
        }
#pragma unroll
        for (int jj = 0; jj < 16; ++jj) P2s[k * 64 + j0 + jj] = acc[jj];
    }
    {
        const int c0 = q * 4;
        float acc[4] = {0.f, 0.f, 0.f, 0.f};
        for (int j = 0; j < 64; ++j) {
            float w = W2s[k * 64 + j];
#pragma unroll
            for (int cc = 0; cc < 4; ++cc) acc[cc] += w * C3[j * 16 + c0 + cc];
        }
#pragma unroll
        for (int cc = 0; cc < 4; ++cc) R3s[k * 16 + c0 + cc] = acc[cc];
    }
    if (q == 0) {
        float a = 0.f;
        for (int j = 0; j < 64; ++j) a += W2s[k * 64 + j] * W3s[j];
        r3[k] = a;
    }
    if (q == 1) {
        float a = 0.f;
        for (int m = 0; m < 64; ++m) a += b0s[m] * W1s[m * 64 + k];
        rb1[k] = a;
    }
    if (q == 2) {
        float a = 0.f;
        for (int m = 0; m < 64; ++m) a += b1s[m] * W2s[m * 64 + k];
        rb2[k] = a;
    }
    __syncthreads();

    // phase 2: Q1 = W0 C1 ; Q2 = P2 C2 ; Q3 = P2 R3 ; v = P2 r3 ; rb12 = rb1 W2
    {
        const int c0 = q * 4;
        float q1[4] = {0,0,0,0}, q2[4] = {0,0,0,0}, q3[4] = {0,0,0,0};
        for (int j = 0; j < 64; ++j) {
            float w0 = W0s[k * 64 + j], p2 = P2s[k * 64 + j];
#pragma unroll
            for (int cc = 0; cc < 4; ++cc) {
                q1[cc] += w0 * C1[j * 16 + c0 + cc];
                q2[cc] += p2 * C2[j * 16 + c0 + cc];
                q3[cc] += p2 * R3s[j * 16 + c0 + cc];
            }
        }
#pragma unroll
        for (int cc = 0; cc < 4; ++cc) {
            K[KQ1 + k * 16 + c0 + cc] = q1[cc];
            K[KQ2 + k * 16 + c0 + cc] = q2[cc];
            K[KQ3 + k * 16 + c0 + cc] = q3[cc];
        }
    }
    if (q == 3) {
        float a = 0.f;
        for (int j = 0; j < 64; ++j) a += P2s[k * 64 + j] * r3[j];
        K[KV + k] = a;
    }
    if (q == 0) {
        float a = 0.f;
        for (int m = 0; m < 64; ++m) a += rb1[m] * W2s[m * 64 + k];
        rb12[k] = a;
    }
    __syncthreads();

    // phase 3: bias projections
    if (t < 16) {
        float a1 = 0.f, a2 = 0.f, ad = 0.f;
        for (int j = 0; j < 64; ++j) {
            a1 += rb1[j] * C2[j * 16 + t] + rb2[j] * C3[j * 16 + t];
            a2 += rb12[j] * C3[j * 16 + t];
            ad += b0s[j] * C1[j * 16 + t] + b1s[j] * C2[j * 16 + t]
                + b2s[j] * C3[j * 16 + t];
        }
        K[KU1 + t] = a1; K[KU2 + t] = a2; K[KD + t] = ad + cb[t];
    }
    if (t == 0) {
        float al = 0.f, be = 0.f, ga = 0.f;
        for (int j = 0; j < 64; ++j) {
            al += rb12[j] * W3s[j]; be += rb2[j] * W3s[j]; ga += b2s[j] * W3s[j];
        }
        K[KSC + 0] = al; K[KSC + 1] = be; K[KSC + 2] = ga;
    }
}

// ---------------- fused layer: 4 nodes / wave, 8B-per-lane gathers ---------
// Quarter q (16 lanes) owns node nn; lane m covers feature quad 4m..4m+3
// (u64 = 4 bf16). One gather instruction fetches a full 128B row per quarter.
// (round-13 form: no sw prefetch — measured faster than the round-14 variant)
template <int LAYER>
__global__ __launch_bounds__(256) void k_layer(
    const ushort* __restrict__ Min,      // bf16 rows [*,64]
    const int2* __restrict__ edges,
    const int* __restrict__ row_ptr,
    const float* __restrict__ K,
    const float* __restrict__ s1in,
    const float* __restrict__ s2in,
    ushort* __restrict__ Mout,           // bf16 rows [*,64]
    float* __restrict__ s_out,
    float* __restrict__ t4,
    float* __restrict__ out) {
    __shared__ float QT[64 * 17];   // Q_LAYER, padded stride 17
    const int tid = threadIdx.x;
    constexpr int KQ = (LAYER == 0) ? KQ1 : (LAYER == 1) ? KQ2 : KQ3;
    for (int i = tid; i < 1024; i += 256) {
        int j = i >> 4, c = i & 15;
        QT[j * 17 + c] = K[KQ + i];
    }
    const int lane = tid & 63;
    const int w    = tid >> 6;
    const int q    = lane >> 4;          // quarter = node within group of 4
    const int m    = lane & 15;          // feature-quad index
    float v0 = 0.f, v1 = 0.f, v2 = 0.f, v3 = 0.f;
    if constexpr (LAYER == 2) {
        v0 = K[KV + 4 * m + 0]; v1 = K[KV + 4 * m + 1];
        v2 = K[KV + 4 * m + 2]; v3 = K[KV + 4 * m + 3];
    }
    __syncthreads();

    const int nn = blockIdx.x * 16 + w * 4 + q;     // grid = N/16 blocks
    const int rp0 = row_ptr[nn], rp1 = row_ptr[nn + 1];
    const int d = rp1 - rp0;
    int dmax = max(d, __shfl_xor(d, 16));
    dmax = max(dmax, __shfl_xor(dmax, 32));
    const int trips = __builtin_amdgcn_readfirstlane((dmax + 7) >> 3);

    float a0 = 0.f, a1 = 0.f, a2 = 0.f, a3 = 0.f, accs = 0.f;
    for (int t = 0; t < trips; ++t) {
        const int base = rp0 + t * 8;
        int col[8]; float wv[8];
#pragma unroll
        for (int i = 0; i < 8; ++i) {
            int pi = base + i;
            int pc = min(pi, rp1 - 1);          // clamp inside own row
            int2 e = edges[pc];                  // same addr within quarter
            col[i] = e.x;
            wv[i] = (pi < rp1) ? __int_as_float(e.y) : 0.f;
        }
        unsigned long long g[8];
#pragma unroll
        for (int i = 0; i < 8; ++i)
            g[i] = *(const unsigned long long*)(Min + col[i] * 64 + 4 * m);
        if constexpr (LAYER == 0) {
#pragma unroll
            for (int i = 0; i < 8; ++i) accs += wv[i];
        }
#pragma unroll
        for (int i = 0; i < 8; ++i) {
            unsigned int lo = (unsigned int)g[i];
            unsigned int hi = (unsigned int)(g[i] >> 32);
            union { unsigned int u; float f; } x0, x1, x2, x3;
            x0.u = lo << 16; x1.u = lo & 0xFFFF0000u;
            x2.u = hi << 16; x3.u = hi & 0xFFFF0000u;
            a0 += wv[i] * x0.f; a1 += wv[i] * x1.f;
            a2 += wv[i] * x2.f; a3 += wv[i] * x3.f;
        }
    }

    if constexpr (LAYER < 2) {
        unsigned long long pk =
              (unsigned long long)f2bf(a0)
            | ((unsigned long long)f2bf(a1) << 16)
            | ((unsigned long long)f2bf(a2) << 32)
            | ((unsigned long long)f2bf(a3) << 48);
        ((unsigned long long*)Mout)[nn * 16 + m] = pk;  // 128B / quarter
    }
    if constexpr (LAYER == 0) {
        if (m == 0) s_out[nn] = accs;   // accs uniform within quarter
    }
    if constexpr (LAYER == 1) {
        // s2[nn] = sum_p wgt * s1[col]  (edges spread over quarter's 16 lanes)
        float ss = 0.f;
        for (int p = rp0 + m; p < rp1; p += 16) {
            int2 e = edges[p];
            ss += __int_as_float(e.y) * s1in[e.x];
        }
        ss += __shfl_xor(ss, 1); ss += __shfl_xor(ss, 2);
        ss += __shfl_xor(ss, 4); ss += __shfl_xor(ss, 8);
        if (m == 0) s_out[nn] = ss;
    }

    float s1n = 0.f, s2n = 0.f;
    if constexpr (LAYER == 2) {
        s1n = s1in[nn]; s2n = s2in[nn];
        float tv = a0 * v0 + a1 * v1 + a2 * v2 + a3 * v3;
        tv += __shfl_xor(tv, 1); tv += __shfl_xor(tv, 2);
        tv += __shfl_xor(tv, 4); tv += __shfl_xor(tv, 8);
        if (m == 0)
            t4[nn] = tv + K[KSC + 0] * s2n + K[KSC + 1] * s1n + K[KSC + 2];
    }

    // projection: lane computes channel c = m for its OWN node (no reduce)
    float r = 0.f;
#pragma unroll
    for (int a = 0; a < 16; ++a) {
        int srcl = (q << 4) + a;     // stay within quarter
        float f0 = __shfl(a0, srcl), f1 = __shfl(a1, srcl);
        float f2 = __shfl(a2, srcl), f3 = __shfl(a3, srcl);
        r += f0 * QT[(4 * a + 0) * 17 + m] + f1 * QT[(4 * a + 1) * 17 + m]
           + f2 * QT[(4 * a + 2) * 17 + m] + f3 * QT[(4 * a + 3) * 17 + m];
    }
    {
        int o = nn * NC + m;         // 64 lanes = 4 full out rows, contiguous
        if constexpr (LAYER == 0) {
            out[o] = K[KD + m] + r;
        } else if constexpr (LAYER == 1) {
            out[o] += r;
        } else {
            out[o] += r + s1n * K[KU1 + m] + s2n * K[KU2 + m];
        }
    }
}

// h4 = b3 + agg(t4); out[n, :] += h4 * conv_w[:, 192]   (thread per node)
__global__ __launch_bounds__(256) void k_agg4_out(
    const float* __restrict__ t4, const int2* __restrict__ edges,
    const int* __restrict__ row_ptr, const float* __restrict__ b3,
    const float* __restrict__ conv_w, float* __restrict__ out) {
    int n = blockIdx.x * blockDim.x + threadIdx.x;
    if (n >= N) return;
    int p0 = row_ptr[n], p1 = row_ptr[n + 1];
    float a0 = 0.f, a1 = 0.f;
    for (int p = p0; p < p1; p += 4) {
        int q0 = min(p, p1 - 1), q1 = min(p + 1, p1 - 1);
        int q2 = min(p + 2, p1 - 1), q3 = min(p + 3, p1 - 1);
        int2 e0 = edges[q0], e1 = edges[q1], e2 = edges[q2], e3 = edges[q3];
        float w0 = __int_as_float(e0.y);
        float w1 = (p + 1 < p1) ? __int_as_float(e1.y) : 0.f;
        float w2 = (p + 2 < p1) ? __int_as_float(e2.y) : 0.f;
        float w3 = (p + 3 < p1) ? __int_as_float(e3.y) : 0.f;
        a0 += w0 * t4[e0.x]; a1 += w1 * t4[e1.x];
        a0 += w2 * t4[e2.x]; a1 += w3 * t4[e3.x];
    }
    float h4 = a0 + a1 + b3[0];
    float4* o4 = (float4*)(out + n * NC);
#pragma unroll
    for (int k = 0; k < 4; ++k) {
        float4 v = o4[k];
        v.x += h4 * conv_w[(4 * k + 0) * TOT + 192];
        v.y += h4 * conv_w[(4 * k + 1) * TOT + 192];
        v.z += h4 * conv_w[(4 * k + 2) * TOT + 192];
        v.w += h4 * conv_w[(4 * k + 3) * TOT + 192];
        o4[k] = v;
    }
}

// ---------------- launch ----------------

extern "C" void kernel_launch(void* const* d_in, const int* in_sizes, int n_in,
                              void* d_out, int out_size, void* d_ws, size_t ws_size,
                              hipStream_t stream) {
    const float* x   = (const float*)d_in[0];
    const int*   ei  = (const int*)d_in[1];
    const int*   src = ei;
    const int*   dst = ei + E;
    const float* W0  = (const float*)d_in[3];
    const float* b0  = (const float*)d_in[4];
    const float* W1  = (const float*)d_in[5];
    const float* b1  = (const float*)d_in[6];
    const float* W2  = (const float*)d_in[7];
    const float* b2  = (const float*)d_in[8];
    const float* W3  = (const float*)d_in[9];
    const float* b3  = (const float*)d_in[10];
    const float* cw  = (const float*)d_in[11];
    const float* cb  = (const float*)d_in[12];
    float* out = (float*)d_out;

    char* p = (char*)d_ws;
    auto alloc = [&](size_t nbytes) {
        char* r = p;
        p += (nbytes + 255) & ~(size_t)255;
        return (void*)r;
    };
    int*    degp    = (int*)alloc((size_t)N * DP * 4);   // padded: 1/line
    int*    pos     = (int*)alloc((size_t)E * 4);
    int*    row_ptr = (int*)alloc((size_t)(N + 1) * 4);
    float*  dinv    = (float*)alloc((size_t)N * 4);
    int*    part    = (int*)alloc((size_t)NB * 4);
    int2*   edges   = (int2*)alloc((size_t)(E + N) * 8);
    ushort* xb      = (ushort*)alloc((size_t)N * 64 * 2);
    ushort* M1      = (ushort*)alloc((size_t)N * 64 * 2);
    ushort* M2      = (ushort*)alloc((size_t)N * 64 * 2);
    float*  s1      = (float*)alloc((size_t)N * 4);
    float*  s2      = (float*)alloc((size_t)N * 4);
    float*  t4      = (float*)alloc((size_t)N * 4);
    float*  K       = (float*)alloc((size_t)KSZ * 4);

    // weight-product setup + x->bf16 + degp zeroing
    k_setup<<<1, 256, 0, stream>>>(W0, b0, W1, b1, W2, b2, W3, b3, cw, cb, K);
    k_xbf<<<(N * 64 / 4 + 255) / 256, 256, 0, stream>>>(x, xb, degp);

    // graph preprocessing (scanpart folded into k_scatter; self-loop too)
    k_count  <<<(E / 4 + 255) / 256, 256, 0, stream>>>(dst, degp, pos);
    k_part   <<<NB, 256, 0, stream>>>(degp, part);
    k_scatter<<<NB, 256, 0, stream>>>(degp, part, row_ptr, dinv, edges);
    k_fill   <<<(E + 255) / 256, 256, 0, stream>>>(src, dst, pos, row_ptr, dinv, edges);

    const int layerGrid = N / 16;   // 4 nodes / wave, 4 waves / block

    k_layer<0><<<layerGrid, 256, 0, stream>>>(
        xb, edges, row_ptr, K, nullptr, nullptr, M1, s1, nullptr, out);
    k_layer<1><<<layerGrid, 256, 0, stream>>>(
        M1, edges, row_ptr, K, s1, nullptr, M2, s2, nullptr, out);
    k_layer<2><<<layerGrid, 256, 0, stream>>>(
        M2, edges, row_ptr, K, s1, s2, nullptr, nullptr, t4, out);
    k_agg4_out<<<(N + 255) / 256, 256, 0, stream>>>(t4, edges, row_ptr, b3, cw, out);
}